// Round 14
// baseline (151.953 us; speedup 1.0000x reference)
//
#include <hip/hip_runtime.h>

#define TWO_M 512
#define NCOL  64
#define SK    136        // bf16 per Yt row (128 k + 8 pad) = 272 B
#define SKW   68         // u32 words per Yt row
#define SG    68         // f32 stride of Gl rows

typedef short short8 __attribute__((ext_vector_type(8)));
typedef float f32x4  __attribute__((ext_vector_type(4)));

static __device__ __forceinline__ unsigned int f2bf(float f) {
    unsigned int u = __builtin_bit_cast(unsigned int, f);
    return (u + 0x7fffu + ((u >> 16) & 1u)) >> 16;   // RNE
}
static __device__ __forceinline__ float bflo(unsigned int p) {
    return __builtin_bit_cast(float, p << 16);
}
static __device__ __forceinline__ float bfhi(unsigned int p) {
    return __builtin_bit_cast(float, p & 0xffff0000u);
}

// swizzled bf16 fragment read
#define FRAG(row, k0) (*(const short8*)&Yt[(row) * SK + ((((k0) >> 3) ^ (((row) >> 2) & 7)) << 3)])

// One block per batch, y read ONCE, P3 from retained registers.
// LDS 35328 B + VGPR<=64 -> 4 blocks/CU (32 waves).
//   Yt bf16[64][SK] @0      (17408)
//   Gl f32 [64][SG] @17408  (17408)
//   bd f32 [128]    @34816  (  512)
__global__ __launch_bounds__(512, 8) void gs_fused(const float* __restrict__ y,
                                                   float* __restrict__ out)
{
    __shared__ __align__(16) unsigned char smem[35328];
    unsigned short* Yt   = (unsigned short*)smem;
    unsigned int*   Yt32 = (unsigned int*)smem;
    float*          Gl   = (float*)(smem + 17408);
    float*          bd   = (float*)(smem + 34816);

    const int   batch = blockIdx.x;
    const float* Y    = y + (size_t)batch * (TWO_M * NCOL);
    const int   tid   = threadIdx.x;
    const int   wave  = tid >> 6;
    const int   lane  = tid & 63;
    const int   cq    = tid & 15;

    f32x4 acc0 = {0, 0, 0, 0}, acc1 = {0, 0, 0, 0};
    const int arow = 16 * (wave >> 1) + (lane & 15);
    const int bc0  = 32 * (wave & 1) + (lane & 15);
    const int koff = (lane >> 4) * 8;

    const int kp0 = tid >> 4;               // k-pair 0..31
    const int kp1 = 32 + kp0;               // k-pair 32..63
    const int ws0 = ((((kp0 >> 2) ^ (cq & 7)) << 2) | (kp0 & 3));
    const int ws1 = ((((kp1 >> 2) ^ (cq & 7)) << 2) | (kp1 & 3));
    const int c0r = 4 * cq;
    const int ia0 = kp0 * 32 + cq, ib0 = kp0 * 32 + 16 + cq;
    const int ia1 = kp1 * 32 + cq, ib1 = kp1 * 32 + 16 + cq;

    // retained bf16-packed y (32 VGPRs)
    unsigned int pk[4][8];

    // ---------------- Phase 1: Gram via MFMA, 4 chunks, single buffer ----------------
    float4 va0, vb0, va1, vb1;
    {
        const float4* src = (const float4*)Y;
        va0 = src[ia0]; vb0 = src[ib0];
        va1 = src[ia1]; vb1 = src[ib1];
    }
#pragma unroll
    for (int c = 0; c < 4; ++c) {
        pk[c][0] = f2bf(va0.x) | (f2bf(vb0.x) << 16);
        pk[c][1] = f2bf(va0.y) | (f2bf(vb0.y) << 16);
        pk[c][2] = f2bf(va0.z) | (f2bf(vb0.z) << 16);
        pk[c][3] = f2bf(va0.w) | (f2bf(vb0.w) << 16);
        pk[c][4] = f2bf(va1.x) | (f2bf(vb1.x) << 16);
        pk[c][5] = f2bf(va1.y) | (f2bf(vb1.y) << 16);
        pk[c][6] = f2bf(va1.z) | (f2bf(vb1.z) << 16);
        pk[c][7] = f2bf(va1.w) | (f2bf(vb1.w) << 16);
        if (c < 3) {   // next chunk's loads fly under barriers + MFMA
            const float4* src = (const float4*)(Y + (size_t)(c + 1) * 128 * NCOL);
            va0 = src[ia0]; vb0 = src[ib0];
            va1 = src[ia1]; vb1 = src[ib1];
        }
        if (c) __syncthreads();               // MFMA of c-1 done reading Yt
#pragma unroll
        for (int j = 0; j < 4; ++j) {
            Yt32[(c0r + j) * SKW + ws0] = pk[c][j];
            Yt32[(c0r + j) * SKW + ws1] = pk[c][4 + j];
        }
        __syncthreads();
#pragma unroll
        for (int kb = 0; kb < 128; kb += 32) {
            const short8 af  = FRAG(arow, kb + koff);
            const short8 bf0 = FRAG(bc0, kb + koff);
            const short8 bf1 = FRAG(bc0 + 16, kb + koff);
            acc0 = __builtin_amdgcn_mfma_f32_16x16x32_bf16(af, bf0, acc0, 0, 0, 0);
            acc1 = __builtin_amdgcn_mfma_f32_16x16x32_bf16(af, bf1, acc1, 0, 0, 0);
        }
    }
    __syncthreads();   // MFMA chunk 3 done before Gl overwrites nothing (Gl disjoint) — keep for safety of Yt reuse semantics

    // ---------------- G slab write (disjoint per wave) ----------------
#pragma unroll
    for (int j = 0; j < 4; ++j) {
        const int gr = 16 * (wave >> 1) + (lane >> 4) * 4 + j;
        Gl[gr * SG + 32 * (wave & 1) + (lane & 15)]      = acc0[j];
        Gl[gr * SG + 32 * (wave & 1) + 16 + (lane & 15)] = acc1[j];
    }
    __syncthreads();

    // ---------------- Phase 2: wave-0 scalar recurrence -> bd (alpha, invd) ----------------
    if (wave == 0) {
        const int l = lane;
        const float d     = Gl[l * SG + l];
        const float invd  = 1.0f / d;
        const float invd0 = __shfl(invd, 0);
        float T  = Gl[l] * invd0;
        float r  = T;
        float Nq = __shfl(T, 0) * invd0;
        float bj = __shfl(r, 1);
        float bsave = 0.f;
        float grow = Gl[SG + l];
        for (int j = 1; j < 64; ++j) {
            const float grow_next = Gl[(j < 63 ? j + 1 : 63) * SG + l];
            const float invdj = __shfl(invd, j);
            const float Tprev = T;
            T = (grow - bj * Tprev) * invdj;
            const float cj = (__shfl(Tprev, j) - bj * Nq) * invdj;
            Nq = (__shfl(T, j) - bj * cj) * invdj;
            r  = T - r * cj;
            if (l == j) bsave = bj;
            bj = __shfl(r, (j + 1) & 63);
            grow = grow_next;
        }
        bd[l]      = -bsave * invd;          // alpha_l
        bd[64 + l] = invd;
    }
    __syncthreads();

    // ---------------- Phase 3: apply from retained registers, NT stores, zero loads ----------------
    const float a0 = bd[c0r],      a1 = bd[c0r + 1];
    const float a2 = bd[c0r + 2],  a3 = bd[c0r + 3];
    const float i0 = bd[64 + c0r],     i1 = bd[64 + c0r + 1];
    const float i2 = bd[64 + c0r + 2], i3 = bd[64 + c0r + 3];
    f32x4* o4 = (f32x4*)(out + (size_t)batch * (TWO_M * NCOL));

#pragma unroll
    for (int c = 0; c < 4; ++c) {
#pragma unroll
        for (int pr = 0; pr < 2; ++pr) {
            const int rbase = 128 * c + 2 * (pr ? kp1 : kp0);
            const unsigned int u0 = pk[c][4 * pr + 0];
            const unsigned int u1 = pk[c][4 * pr + 1];
            const unsigned int u2 = pk[c][4 * pr + 2];
            const unsigned int u3 = pk[c][4 * pr + 3];
#pragma unroll
            for (int h = 0; h < 2; ++h) {
                const float y0 = h ? bfhi(u0) : bflo(u0);
                const float y1 = h ? bfhi(u1) : bflo(u1);
                const float y2 = h ? bfhi(u2) : bflo(u2);
                const float y3 = h ? bfhi(u3) : bflo(u3);
                const float b0 = y0 * i0, b1 = y1 * i1, b2 = y2 * i2, b3 = y3 * i3;
                float A = a0, C = b0;
                A = a1 * A; C = fmaf(a1, C, b1);
                A = a2 * A; C = fmaf(a2, C, b2);
                A = a3 * A; C = fmaf(a3, C, b3);
#pragma unroll
                for (int dlt = 1; dlt < 16; dlt <<= 1) {
                    const float Ap = __shfl_up(A, dlt, 16);
                    const float Cp = __shfl_up(C, dlt, 16);
                    const bool ok = (cq >= dlt);
                    C = ok ? fmaf(A, Cp, C) : C;
                    A = ok ? (A * Ap) : A;
                }
                float qin = __shfl_up(C, 1, 16);
                if (cq == 0) qin = 0.f;
                const float q0 = fmaf(a0, qin, b0);
                const float q1 = fmaf(a1, q0, b1);
                const float q2 = fmaf(a2, q1, b2);
                const float q3 = fmaf(a3, q2, b3);
                __builtin_nontemporal_store(f32x4{q0, q1, q2, q3},
                                            &o4[(rbase + h) * 16 + cq]);
            }
        }
    }
}

extern "C" void kernel_launch(void* const* d_in, const int* in_sizes, int n_in,
                              void* d_out, int out_size, void* d_ws, size_t ws_size,
                              hipStream_t stream)
{
    const float* y = (const float*)d_in[0];
    float* out = (float*)d_out;
    const int B = in_sizes[0] / (TWO_M * NCOL);
    gs_fused<<<dim3(B), dim3(512), 0, stream>>>(y, out);
}

// Round 15
// 94.263 us; speedup vs baseline: 1.6120x; 1.6120x over previous
//
#include <hip/hip_runtime.h>

#define TWO_M 512
#define NCOL  64
#define SK    136        // bf16 per Yt row (128 k + 8 pad) = 272 B
#define SKW   68         // u32 words per Yt row
#define SG    68         // f32 stride of Gl rows

typedef short short8 __attribute__((ext_vector_type(8)));
typedef float f32x4  __attribute__((ext_vector_type(4)));

static __device__ __forceinline__ unsigned int f2bf(float f) {
    unsigned int u = __builtin_bit_cast(unsigned int, f);
    return (u + 0x7fffu + ((u >> 16) & 1u)) >> 16;   // RNE
}
static __device__ __forceinline__ float bflo(unsigned int p) {
    return __builtin_bit_cast(float, p << 16);
}
static __device__ __forceinline__ float bfhi(unsigned int p) {
    return __builtin_bit_cast(float, p & 0xffff0000u);
}

// swizzled bf16 fragment read from buffer `base`
#define FRAGP(base, row, k0) (*(const short8*)&(base)[(row) * SK + ((((k0) >> 3) ^ (((row) >> 2) & 7)) << 3)])

// One block per batch, y read ONCE, P3 from retained registers, NT stores.
// LDS 35840 B -> 4 blocks/CU; VGPR ~60 under (512,4) cap -> no spill.
//   Yt0 bf16[64][SK] @0       (17408)  -- staging buf 0; REUSED as Gl after P1
//   Yt1 bf16[64][SK] @17408   (17408)  -- staging buf 1
//   bd  f32 [128]    @34816   (  512)
// Overlay safety: Yt0's last reader is MFMA(c=2); its ds_reads are retired before
// each wave arrives at the c=3 barrier, so post-loop writes to Gl(=Yt0) are race-free.
__global__ __launch_bounds__(512, 4) void gs_fused(const float* __restrict__ y,
                                                   float* __restrict__ out)
{
    __shared__ __align__(16) unsigned char smem[35840];
    unsigned short* Yt0 = (unsigned short*)smem;
    unsigned short* Yt1 = (unsigned short*)(smem + 17408);
    unsigned int*   Yw0 = (unsigned int*)smem;
    unsigned int*   Yw1 = (unsigned int*)(smem + 17408);
    float*          Gl  = (float*)smem;            // overlays Yt0
    float*          bd  = (float*)(smem + 34816);

    const int   batch = blockIdx.x;
    const float* Y    = y + (size_t)batch * (TWO_M * NCOL);
    const int   tid   = threadIdx.x;
    const int   wave  = tid >> 6;
    const int   lane  = tid & 63;
    const int   cq    = tid & 15;

    f32x4 acc0 = {0, 0, 0, 0}, acc1 = {0, 0, 0, 0};
    const int arow = 16 * (wave >> 1) + (lane & 15);
    const int bc0  = 32 * (wave & 1) + (lane & 15);
    const int koff = (lane >> 4) * 8;

    const int kp0 = tid >> 4;               // k-pair 0..31
    const int kp1 = 32 + kp0;               // k-pair 32..63
    const int ws0 = ((((kp0 >> 2) ^ (cq & 7)) << 2) | (kp0 & 3));
    const int ws1 = ((((kp1 >> 2) ^ (cq & 7)) << 2) | (kp1 & 3));
    const int c0r = 4 * cq;
    const int ia0 = kp0 * 32 + cq, ib0 = kp0 * 32 + 16 + cq;
    const int ia1 = kp1 * 32 + cq, ib1 = kp1 * 32 + 16 + cq;

    // retained bf16-packed y (32 VGPRs)
    unsigned int pk[4][8];

    // ---------------- Phase 1: Gram via MFMA, 4 chunks, dbuf (1 barrier/chunk) ----------------
    float4 va0, vb0, va1, vb1;
    {
        const float4* src = (const float4*)Y;
        va0 = src[ia0]; vb0 = src[ib0];
        va1 = src[ia1]; vb1 = src[ib1];
    }
#pragma unroll
    for (int c = 0; c < 4; ++c) {
        pk[c][0] = f2bf(va0.x) | (f2bf(vb0.x) << 16);
        pk[c][1] = f2bf(va0.y) | (f2bf(vb0.y) << 16);
        pk[c][2] = f2bf(va0.z) | (f2bf(vb0.z) << 16);
        pk[c][3] = f2bf(va0.w) | (f2bf(vb0.w) << 16);
        pk[c][4] = f2bf(va1.x) | (f2bf(vb1.x) << 16);
        pk[c][5] = f2bf(va1.y) | (f2bf(vb1.y) << 16);
        pk[c][6] = f2bf(va1.z) | (f2bf(vb1.z) << 16);
        pk[c][7] = f2bf(va1.w) | (f2bf(vb1.w) << 16);
        if (c < 3) {   // next chunk's loads fly under ds_write + barrier + MFMA
            const float4* src = (const float4*)(Y + (size_t)(c + 1) * 128 * NCOL);
            va0 = src[ia0]; vb0 = src[ib0];
            va1 = src[ia1]; vb1 = src[ib1];
        }
        unsigned int* Yw = (c & 1) ? Yw1 : Yw0;
#pragma unroll
        for (int j = 0; j < 4; ++j) {
            Yw[(c0r + j) * SKW + ws0] = pk[c][j];
            Yw[(c0r + j) * SKW + ws1] = pk[c][4 + j];
        }
        __syncthreads();   // buf(c&1) fully written; MFMA(c-2) reads of this buf retired
        const unsigned short* Yt = (c & 1) ? Yt1 : Yt0;
#pragma unroll
        for (int kb = 0; kb < 128; kb += 32) {
            const short8 af  = FRAGP(Yt, arow, kb + koff);
            const short8 bf0 = FRAGP(Yt, bc0, kb + koff);
            const short8 bf1 = FRAGP(Yt, bc0 + 16, kb + koff);
            acc0 = __builtin_amdgcn_mfma_f32_16x16x32_bf16(af, bf0, acc0, 0, 0, 0);
            acc1 = __builtin_amdgcn_mfma_f32_16x16x32_bf16(af, bf1, acc1, 0, 0, 0);
        }
    }

    // ---------------- G slab write into Gl (= Yt0 region; race-free per header note) ----------------
#pragma unroll
    for (int j = 0; j < 4; ++j) {
        const int gr = 16 * (wave >> 1) + (lane >> 4) * 4 + j;
        Gl[gr * SG + 32 * (wave & 1) + (lane & 15)]      = acc0[j];
        Gl[gr * SG + 32 * (wave & 1) + 16 + (lane & 15)] = acc1[j];
    }
    __syncthreads();

    // ---------------- Phase 2: wave-0 scalar recurrence -> bd (alpha, invd) ----------------
    if (wave == 0) {
        const int l = lane;
        const float d     = Gl[l * SG + l];
        const float invd  = 1.0f / d;
        const float invd0 = __shfl(invd, 0);
        float T  = Gl[l] * invd0;
        float r  = T;
        float Nq = __shfl(T, 0) * invd0;
        float bj = __shfl(r, 1);
        float bsave = 0.f;
        float grow = Gl[SG + l];
        for (int j = 1; j < 64; ++j) {
            const float grow_next = Gl[(j < 63 ? j + 1 : 63) * SG + l];
            const float invdj = __shfl(invd, j);
            const float Tprev = T;
            T = (grow - bj * Tprev) * invdj;
            const float cj = (__shfl(Tprev, j) - bj * Nq) * invdj;
            Nq = (__shfl(T, j) - bj * cj) * invdj;
            r  = T - r * cj;
            if (l == j) bsave = bj;
            bj = __shfl(r, (j + 1) & 63);
            grow = grow_next;
        }
        bd[l]      = -bsave * invd;          // alpha_l
        bd[64 + l] = invd;
    }
    __syncthreads();

    // ---------------- Phase 3: apply from retained registers, NT stores, zero loads ----------------
    const float a0 = bd[c0r],      a1 = bd[c0r + 1];
    const float a2 = bd[c0r + 2],  a3 = bd[c0r + 3];
    const float i0 = bd[64 + c0r],     i1 = bd[64 + c0r + 1];
    const float i2 = bd[64 + c0r + 2], i3 = bd[64 + c0r + 3];
    f32x4* o4 = (f32x4*)(out + (size_t)batch * (TWO_M * NCOL));

#pragma unroll
    for (int c = 0; c < 4; ++c) {
#pragma unroll
        for (int pr = 0; pr < 2; ++pr) {
            const int rbase = 128 * c + 2 * (pr ? kp1 : kp0);
            const unsigned int u0 = pk[c][4 * pr + 0];
            const unsigned int u1 = pk[c][4 * pr + 1];
            const unsigned int u2 = pk[c][4 * pr + 2];
            const unsigned int u3 = pk[c][4 * pr + 3];
#pragma unroll
            for (int h = 0; h < 2; ++h) {
                const float y0 = h ? bfhi(u0) : bflo(u0);
                const float y1 = h ? bfhi(u1) : bflo(u1);
                const float y2 = h ? bfhi(u2) : bflo(u2);
                const float y3 = h ? bfhi(u3) : bflo(u3);
                const float b0 = y0 * i0, b1 = y1 * i1, b2 = y2 * i2, b3 = y3 * i3;
                float A = a0, C = b0;
                A = a1 * A; C = fmaf(a1, C, b1);
                A = a2 * A; C = fmaf(a2, C, b2);
                A = a3 * A; C = fmaf(a3, C, b3);
#pragma unroll
                for (int dlt = 1; dlt < 16; dlt <<= 1) {
                    const float Ap = __shfl_up(A, dlt, 16);
                    const float Cp = __shfl_up(C, dlt, 16);
                    const bool ok = (cq >= dlt);
                    C = ok ? fmaf(A, Cp, C) : C;
                    A = ok ? (A * Ap) : A;
                }
                float qin = __shfl_up(C, 1, 16);
                if (cq == 0) qin = 0.f;
                const float q0 = fmaf(a0, qin, b0);
                const float q1 = fmaf(a1, q0, b1);
                const float q2 = fmaf(a2, q1, b2);
                const float q3 = fmaf(a3, q2, b3);
                __builtin_nontemporal_store(f32x4{q0, q1, q2, q3},
                                            &o4[(rbase + h) * 16 + cq]);
            }
        }
    }
}

extern "C" void kernel_launch(void* const* d_in, const int* in_sizes, int n_in,
                              void* d_out, int out_size, void* d_ws, size_t ws_size,
                              hipStream_t stream)
{
    const float* y = (const float*)d_in[0];
    float* out = (float*)d_out;
    const int B = in_sizes[0] / (TWO_M * NCOL);
    gs_fused<<<dim3(B), dim3(512), 0, stream>>>(y, out);
}